// Round 3
// baseline (917.216 us; speedup 1.0000x reference)
//
#include <hip/hip_runtime.h>

typedef __bf16 bf16;
typedef bf16 bf16x8 __attribute__((ext_vector_type(8)));
typedef float f32x4 __attribute__((ext_vector_type(4)));
typedef unsigned int uint;
typedef uint u32x2 __attribute__((ext_vector_type(2)));
typedef uint u32x4 __attribute__((ext_vector_type(4)));
typedef unsigned short u16x8 __attribute__((ext_vector_type(8)));

constexpr int NT = 4096;   // sequence length N
// H = 64, B = 2

__device__ __forceinline__ bf16x8 ld8f(const float* p) {
    f32x4 a = *(const f32x4*)p;
    f32x4 b = *(const f32x4*)(p + 4);
    bf16x8 v;
    v[0] = (bf16)a[0]; v[1] = (bf16)a[1]; v[2] = (bf16)a[2]; v[3] = (bf16)a[3];
    v[4] = (bf16)b[0]; v[5] = (bf16)b[1]; v[6] = (bf16)b[2]; v[7] = (bf16)b[3];
    return v;
}

__device__ __forceinline__ uint pack2(float a, float b) {
    unsigned short ua = __builtin_bit_cast(unsigned short, (bf16)a);
    unsigned short ub = __builtin_bit_cast(unsigned short, (bf16)b);
    return (uint)ua | ((uint)ub << 16);
}

// ---------------------------------------------------------------------------
// Kernel 1: projections q_t = norm(h_t @ Wq[t]^T), k_e = norm(h_pred @ Wk[e]^T)
// (bf16 out), plus vT[p][b][h][n] = bf16 transpose of h_p.
// grid = 128 rowtiles x 3 slices (slice 0: vT + q-proj; 1: k-proj 0-2; 2: k-proj 3-5).
// ---------------------------------------------------------------------------
__global__ __launch_bounds__(256) void prep_kernel(
    const float* __restrict__ h0, const float* __restrict__ h1, const float* __restrict__ h2,
    const float* __restrict__ Wq, const float* __restrict__ Wk,
    bf16* __restrict__ qn, bf16* __restrict__ kn, bf16* __restrict__ vT)
{
    __shared__ __align__(16) unsigned short tlds[4][16][72];
    const int tid = threadIdx.x, wid = tid >> 6, lane = tid & 63;
    const int l15 = lane & 15, quad = lane >> 4;
    const int bx = blockIdx.x;
    const int rt = bx & 127, sl = bx >> 7;       // slice 0..2
    const int g0 = rt * 64;
    const int grow = g0 + wid * 16 + l15;        // A-frag row (global b*N+n)
    const float* hs[3] = {h0, h1, h2};

    bf16x8 af[3][2];
#pragma unroll
    for (int p = 0; p < 3; p++)
#pragma unroll
        for (int hc = 0; hc < 2; hc++)
            af[p][hc] = ld8f(hs[p] + (size_t)grow * 64 + hc * 32 + quad * 8);

    if (sl == 0) {
        const int gr0 = g0 + wid * 16;
        const int bb = gr0 >> 12, n0 = gr0 & 4095;
#pragma unroll
        for (int p = 0; p < 3; p++) {
#pragma unroll
            for (int hc = 0; hc < 2; hc++)
                *(u16x8*)(&tlds[wid][l15][hc * 32 + quad * 8]) = __builtin_bit_cast(u16x8, af[p][hc]);
            unsigned short vals[16];
#pragma unroll
            for (int r = 0; r < 16; r++) vals[r] = tlds[wid][r][lane];
            uint us[8];
#pragma unroll
            for (int k = 0; k < 8; k++) us[k] = (uint)vals[2 * k] | ((uint)vals[2 * k + 1] << 16);
            uint* dst = (uint*)(vT + ((size_t)(p * 2 + bb) * 64 + lane) * NT + n0);
            u32x4 w0 = {us[0], us[1], us[2], us[3]};
            u32x4 w1 = {us[4], us[5], us[6], us[7]};
            *(u32x4*)dst = w0;
            *(u32x4*)(dst + 4) = w1;
        }
    }

    const int predmap[6] = {0, 2, 0, 1, 1, 2};
    const int pj0 = sl * 3;
#pragma unroll
    for (int pi = 0; pi < 3; pi++) {
        const int pj = pj0 + pi;
        const float* W = (pj < 3) ? (Wq + pj * 4096) : (Wk + (pj - 3) * 4096);
        const int src = (pj < 3) ? pj : predmap[pj - 3];
        bf16* outp = (pj < 3) ? (qn + (size_t)pj * 2 * NT * 64)
                              : (kn + (size_t)(pj - 3) * 2 * NT * 64);
        f32x4 s[4];
#pragma unroll
        for (int it = 0; it < 4; it++) {
            f32x4 acc = {0.f, 0.f, 0.f, 0.f};
#pragma unroll
            for (int hc = 0; hc < 2; hc++) {
                bf16x8 wb = ld8f(W + (size_t)(it * 16 + l15) * 64 + hc * 32 + quad * 8);
                acc = __builtin_amdgcn_mfma_f32_16x16x32_bf16(af[src][hc], wb, acc, 0, 0, 0);
            }
            s[it] = acc;
        }
#pragma unroll
        for (int r = 0; r < 4; r++) {
            float ss = s[0][r] * s[0][r] + s[1][r] * s[1][r] + s[2][r] * s[2][r] + s[3][r] * s[3][r];
            ss += __shfl_xor(ss, 1); ss += __shfl_xor(ss, 2);
            ss += __shfl_xor(ss, 4); ss += __shfl_xor(ss, 8);
            float rn = rsqrtf(ss);
            s[0][r] *= rn; s[1][r] *= rn; s[2][r] *= rn; s[3][r] *= rn;
        }
        const int rowbase = g0 + wid * 16 + quad * 4;
#pragma unroll
        for (int it = 0; it < 4; it++)
#pragma unroll
            for (int r = 0; r < 4; r++)
                outp[(size_t)(rowbase + r) * 64 + it * 16 + l15] = (bf16)s[it][r];
    }
}

// ---------------------------------------------------------------------------
// Kernel 2: masked cosine attention, LDS-free. Each wave owns 16 q-rows for
// one (edge, j-chunk), both batches (mask byte read once). K/V MFMA fragments
// are loaded directly from global (12.6 MB working set -> L2/L3 resident).
// No __syncthreads anywhere -> waves fully independent; occupancy is the
// latency hider. grid = 6 edges * 64 qtiles(64 rows) * JC. Unscaled bf16
// partials + mask rowsums to workspace.
// ---------------------------------------------------------------------------
template<int JC>
__global__ __launch_bounds__(256, 5) void attn_kernel(
    const bf16* __restrict__ qn, const bf16* __restrict__ kn, const bf16* __restrict__ vT,
    const float* __restrict__ m00, const float* __restrict__ m20, const float* __restrict__ m01,
    const float* __restrict__ m11, const float* __restrict__ m12, const float* __restrict__ m22,
    bf16* __restrict__ Pacc, float* __restrict__ rsO)
{
    const int tid = threadIdx.x, wid = tid >> 6, lane = tid & 63;
    const int l15 = lane & 15, quad = lane >> 4;
    const int bx = blockIdx.x;
    const int e = bx / (64 * JC);
    const int rem = bx % (64 * JC);
    const int qt = rem / JC, jcv = rem % JC;
    const int qrow = qt * 64 + wid * 16 + l15;     // this lane's q row
    const int qtypemap[6] = {0, 0, 1, 1, 2, 2};
    const int predmap[6]  = {0, 2, 0, 1, 1, 2};
    const float* masks[6] = {m00, m20, m01, m11, m12, m22};
    const float* __restrict__ mask = masks[e];
    const int qtv = qtypemap[e], pv = predmap[e];
    constexpr int JSPAN = NT / JC;
    const int jbeg = jcv * JSPAN;

    // Q fragments (stage-1 B-operand), register resident
    bf16x8 Qf[2][2];
#pragma unroll
    for (int b = 0; b < 2; b++)
#pragma unroll
        for (int hc = 0; hc < 2; hc++)
            Qf[b][hc] = *(const bf16x8*)(qn +
                ((size_t)(qtv * 2 + b) * NT + qrow) * 64 + hc * 32 + quad * 8);

    f32x4 acc2[2][4];   // [b][ht]  (acc^T: row=h, col=query)
#pragma unroll
    for (int b = 0; b < 2; b++)
#pragma unroll
        for (int ht = 0; ht < 4; ht++) {
            f32x4 z = {0.f, 0.f, 0.f, 0.f};
            acc2[b][ht] = z;
        }
    float rsl = 0.f;
    const size_t mrow = (size_t)qrow * NT;
    const size_t kb0 = (size_t)(e * 2) * NT * 64;

#pragma unroll 1
    for (int ji = 0; ji < JSPAN / 64; ji++) {
        const int j0 = jbeg + ji * 64;

        // mask fragments: lane holds mask[qrow][j0 + jt*16 + quad*4 .. +3]
        f32x4 mv[4];
#pragma unroll
        for (int jt = 0; jt < 4; jt++)
            mv[jt] = *(const f32x4*)(mask + mrow + j0 + jt * 16 + quad * 4);
#pragma unroll
        for (int jt = 0; jt < 4; jt++)
            rsl += mv[jt][0] + mv[jt][1] + mv[jt][2] + mv[jt][3];

        // stage 1: S^T tiles (K rows as A, Q as B); mask; pack bf16 pairs
        uint Pd[2][4][2];
#pragma unroll
        for (int jt = 0; jt < 4; jt++)
#pragma unroll
            for (int b = 0; b < 2; b++) {
                f32x4 sc = {0.f, 0.f, 0.f, 0.f};
#pragma unroll
                for (int hc = 0; hc < 2; hc++) {
                    bf16x8 ka = *(const bf16x8*)(kn + kb0 +
                        ((size_t)b * NT + j0 + jt * 16 + l15) * 64 + hc * 32 + quad * 8);
                    sc = __builtin_amdgcn_mfma_f32_16x16x32_bf16(ka, Qf[b][hc], sc, 0, 0, 0);
                }
                sc[0] *= mv[jt][0]; sc[1] *= mv[jt][1];
                sc[2] *= mv[jt][2]; sc[3] *= mv[jt][3];
                Pd[b][jt][0] = pack2(sc[0], sc[1]);
                Pd[b][jt][1] = pack2(sc[2], sc[3]);
            }

#pragma unroll
        for (int b = 0; b < 2; b++) {
            // stage-2 B-fragments (P^T) via ds_bpermute quad shuffle:
            // target (quad tq, col n) vgpr v holds j = c*32 + tq*8 + 2v..2v+1
            // source: tile jt = 2c + (tq>>1), lane quad = (tq&1)*2 + (v>>1), dword = v&1
            uint Bf[2][4];
#pragma unroll
            for (int c = 0; c < 2; c++)
#pragma unroll
                for (int v = 0; v < 4; v++) {
                    int srclane = ((((quad & 1) * 2 + (v >> 1)) * 16 + l15) << 2);
                    int lo = __builtin_amdgcn_ds_bpermute(srclane, (int)Pd[b][2 * c][v & 1]);
                    int hi = __builtin_amdgcn_ds_bpermute(srclane, (int)Pd[b][2 * c + 1][v & 1]);
                    Bf[c][v] = (quad & 2) ? (uint)hi : (uint)lo;
                }

            // stage 2: acc^T += VT · P^T  (VT rows from global, L2/L3-served)
#pragma unroll
            for (int ht = 0; ht < 4; ht++)
#pragma unroll
                for (int c = 0; c < 2; c++) {
                    bf16x8 av = *(const bf16x8*)(vT +
                        ((size_t)((pv * 2 + b) * 64 + ht * 16 + l15)) * NT + j0 + c * 32 + quad * 8);
                    u32x4 t = {Bf[c][0], Bf[c][1], Bf[c][2], Bf[c][3]};
                    bf16x8 bbv = __builtin_bit_cast(bf16x8, t);
                    acc2[b][ht] =
                        __builtin_amdgcn_mfma_f32_16x16x32_bf16(av, bbv, acc2[b][ht], 0, 0, 0);
                }
        }
    }

    // store unscaled bf16 partials: acc^T C-layout -> row n (=col), 4 h per store
#pragma unroll
    for (int b = 0; b < 2; b++)
#pragma unroll
        for (int ht = 0; ht < 4; ht++) {
            u32x2 pk;
            pk[0] = pack2(acc2[b][ht][0], acc2[b][ht][1]);
            pk[1] = pack2(acc2[b][ht][2], acc2[b][ht][3]);
            *(u32x2*)(Pacc + (((size_t)(jcv * 6 + e) * 2 + b) * NT + qrow) * 64 +
                      ht * 16 + quad * 4) = pk;
        }
    // mask rowsums: quads hold disjoint j segments
    {
        float v = rsl;
        v += __shfl_xor(v, 16);
        v += __shfl_xor(v, 32);
        if (quad == 0)
            rsO[(size_t)(jcv * 6 + e) * NT + qrow] = v;
    }
}

// ---------------------------------------------------------------------------
// Kernel 3: combine bf16 partials over JC chunks (acc_t = ΣP/Σrs per edge),
// dt_t = 2*sigmoid(h_t Wdt_t^T + b) - 1, h_tn = h_t + step*dt*u_t, outputs.
// grid = 128 rowtiles x 3 types.
// ---------------------------------------------------------------------------
template<int JC>
__global__ __launch_bounds__(256) void update_kernel(
    const float* __restrict__ x0, const float* __restrict__ h0,
    const float* __restrict__ h1, const float* __restrict__ h2,
    const float* __restrict__ Wsu0, const float* __restrict__ Wsu12,
    const float* __restrict__ Wdt, const float* __restrict__ bdt,
    const float* __restrict__ stepp, const float* __restrict__ oscp,
    const bf16* __restrict__ Pacc, const float* __restrict__ rs,
    float* __restrict__ dout)
{
    const int tid = threadIdx.x, wid = tid >> 6, lane = tid & 63;
    const int l15 = lane & 15, quad = lane >> 4;
    const int bx = blockIdx.x;
    const int rt = bx & 127, t = bx >> 7;
    const int g0 = rt * 64;
    const int grow = g0 + wid * 16 + l15;
    const int n = grow & 4095, bb = grow >> 12;
    const float step = *stepp, osc = *oscp;
    const float* hs[3] = {h0, h1, h2};
    const float* __restrict__ ht_base = hs[t];

    bf16x8 afh[2], afacc[2], afx;
#pragma unroll
    for (int hc = 0; hc < 2; hc++)
        afh[hc] = ld8f(ht_base + (size_t)grow * 64 + hc * 32 + quad * 8);
    if (t == 0) afx = ld8f(x0 + (size_t)grow * 32 + quad * 8);

    float s0 = 0.f, s1 = 0.f;
#pragma unroll
    for (int jc = 0; jc < JC; jc++) {
        s0 += rs[(size_t)(jc * 6 + 2 * t) * NT + n];
        s1 += rs[(size_t)(jc * 6 + 2 * t + 1) * NT + n];
    }
    const float i0 = 1.f / s0, i1 = 1.f / s1;
#pragma unroll
    for (int hc = 0; hc < 2; hc++) {
        float A[8] = {0,0,0,0,0,0,0,0}, Bv[8] = {0,0,0,0,0,0,0,0};
#pragma unroll
        for (int jc = 0; jc < JC; jc++) {
            bf16x8 a = *(const bf16x8*)(Pacc +
                (((size_t)(jc * 6 + 2 * t) * 2 + bb) * NT + n) * 64 + hc * 32 + quad * 8);
            bf16x8 c = *(const bf16x8*)(Pacc +
                (((size_t)(jc * 6 + 2 * t + 1) * 2 + bb) * NT + n) * 64 + hc * 32 + quad * 8);
#pragma unroll
            for (int i = 0; i < 8; i++) { A[i] += (float)a[i]; Bv[i] += (float)c[i]; }
        }
        bf16x8 v;
#pragma unroll
        for (int i = 0; i < 8; i++) v[i] = (bf16)(A[i] * i0 + Bv[i] * i1);
        afacc[hc] = v;
    }

    float bdtv[4];
#pragma unroll
    for (int it = 0; it < 4; it++)
        bdtv[it] = bdt[t * 64 + it * 16 + l15];

#pragma unroll
    for (int it = 0; it < 4; it++) {
        f32x4 z = {0.f, 0.f, 0.f, 0.f};
        f32x4 u = {0.f, 0.f, 0.f, 0.f};
#pragma unroll
        for (int hc = 0; hc < 2; hc++) {
            bf16x8 wb = ld8f(Wdt + (size_t)t * 4096 + (size_t)(it * 16 + l15) * 64 + hc * 32 + quad * 8);
            z = __builtin_amdgcn_mfma_f32_16x16x32_bf16(afh[hc], wb, z, 0, 0, 0);
        }
        if (t == 0) {
            bf16x8 w0 = ld8f(Wsu0 + (size_t)(it * 16 + l15) * 96 + quad * 8);
            u = __builtin_amdgcn_mfma_f32_16x16x32_bf16(afx, w0, u, 0, 0, 0);
#pragma unroll
            for (int kc = 0; kc < 2; kc++) {
                bf16x8 wk = ld8f(Wsu0 + (size_t)(it * 16 + l15) * 96 + 32 + kc * 32 + quad * 8);
                u = __builtin_amdgcn_mfma_f32_16x16x32_bf16(afacc[kc], wk, u, 0, 0, 0);
            }
        } else {
#pragma unroll
            for (int kc = 0; kc < 2; kc++) {
                bf16x8 wk = ld8f(Wsu12 + (size_t)(t - 1) * 4096 + (size_t)(it * 16 + l15) * 64 + kc * 32 + quad * 8);
                u = __builtin_amdgcn_mfma_f32_16x16x32_bf16(afacc[kc], wk, u, 0, 0, 0);
            }
        }
        const int colg = it * 16 + l15;
#pragma unroll
        for (int r = 0; r < 4; r++) {
            int row = g0 + wid * 16 + quad * 4 + r;
            float zz = z[r] + bdtv[it];
            float dtv = 2.f / (1.f + __expf(-zz)) - 1.f;
            float hval = ht_base[(size_t)row * 64 + colg];
            float hn = hval + step * dtv * u[r];
            dout[65536 + (size_t)t * 524288 + (size_t)row * 64 + colg] = hn;
            if (t == 2 && colg < 8)
                dout[(size_t)row * 8 + colg] = osc * hn;
        }
    }
}

extern "C" void kernel_launch(void* const* d_in, const int* in_sizes, int n_in,
                              void* d_out, int out_size, void* d_ws, size_t ws_size,
                              hipStream_t stream) {
    const float* x0   = (const float*)d_in[0];
    const float* h0   = (const float*)d_in[1];
    const float* h1   = (const float*)d_in[2];
    const float* h2   = (const float*)d_in[3];
    const float* m00  = (const float*)d_in[4];
    const float* m20  = (const float*)d_in[5];
    const float* m01  = (const float*)d_in[6];
    const float* m11  = (const float*)d_in[7];
    const float* m12  = (const float*)d_in[8];
    const float* m22  = (const float*)d_in[9];
    const float* Wq   = (const float*)d_in[10];
    const float* Wk   = (const float*)d_in[11];
    const float* Wsu0 = (const float*)d_in[12];
    const float* Wsu12= (const float*)d_in[13];
    const float* Wdt  = (const float*)d_in[14];
    const float* bdt  = (const float*)d_in[15];
    const float* step = (const float*)d_in[16];
    const float* oscl = (const float*)d_in[17];

    // workspace layout (element counts)
    bf16* qn  = (bf16*)d_ws;                    // 3*2*4096*64 = 1,572,864
    bf16* kn  = qn + 1572864;                   // 6*2*4096*64 = 3,145,728
    bf16* vT  = kn + 3145728;                   // 3*2*64*4096 = 1,572,864
    bf16* Pacc = vT + 1572864;                  // JC*6*2*4096*64 bf16
    // rs follows: JC*6*4096 floats

    // bytes: 12,582,912 + JC*6,291,456 (Pacc) + JC*98,304 (rs)
    auto need = [](size_t jc) { return 12582912 + jc * 6291456 + jc * 98304; };
    const int JC = (ws_size >= need(8)) ? 8 : ((ws_size >= need(4)) ? 4 : 2);

    prep_kernel<<<384, 256, 0, stream>>>(h0, h1, h2, Wq, Wk, qn, kn, vT);

    if (JC == 8) {
        float* rs = (float*)(Pacc + (size_t)8 * 3145728);
        attn_kernel<8><<<6 * 64 * 8, 256, 0, stream>>>(qn, kn, vT, m00, m20, m01, m11, m12, m22, Pacc, rs);
        update_kernel<8><<<384, 256, 0, stream>>>(x0, h0, h1, h2, Wsu0, Wsu12, Wdt, bdt,
                                                  step, oscl, Pacc, rs, (float*)d_out);
    } else if (JC == 4) {
        float* rs = (float*)(Pacc + (size_t)4 * 3145728);
        attn_kernel<4><<<6 * 64 * 4, 256, 0, stream>>>(qn, kn, vT, m00, m20, m01, m11, m12, m22, Pacc, rs);
        update_kernel<4><<<384, 256, 0, stream>>>(x0, h0, h1, h2, Wsu0, Wsu12, Wdt, bdt,
                                                  step, oscl, Pacc, rs, (float*)d_out);
    } else {
        float* rs = (float*)(Pacc + (size_t)2 * 3145728);
        attn_kernel<2><<<6 * 64 * 2, 256, 0, stream>>>(qn, kn, vT, m00, m20, m01, m11, m12, m22, Pacc, rs);
        update_kernel<2><<<384, 256, 0, stream>>>(x0, h0, h1, h2, Wsu0, Wsu12, Wdt, bdt,
                                                  step, oscl, Pacc, rs, (float*)d_out);
    }
}

// Round 4
// 493.981 us; speedup vs baseline: 1.8568x; 1.8568x over previous
//
#include <hip/hip_runtime.h>

typedef __bf16 bf16;
typedef bf16 bf16x8 __attribute__((ext_vector_type(8)));
typedef float f32x4 __attribute__((ext_vector_type(4)));
typedef unsigned int uint;
typedef uint u32x4 __attribute__((ext_vector_type(4)));
typedef unsigned short u16x8 __attribute__((ext_vector_type(8)));

constexpr int NT = 4096;   // sequence length N
// H = 64, B = 2

__device__ __forceinline__ bf16x8 ld8f(const float* p) {
    f32x4 a = *(const f32x4*)p;
    f32x4 b = *(const f32x4*)(p + 4);
    bf16x8 v;
    v[0] = (bf16)a[0]; v[1] = (bf16)a[1]; v[2] = (bf16)a[2]; v[3] = (bf16)a[3];
    v[4] = (bf16)b[0]; v[5] = (bf16)b[1]; v[6] = (bf16)b[2]; v[7] = (bf16)b[3];
    return v;
}

__device__ __forceinline__ uint pack2(float a, float b) {
    unsigned short ua = __builtin_bit_cast(unsigned short, (bf16)a);
    unsigned short ub = __builtin_bit_cast(unsigned short, (bf16)b);
    return (uint)ua | ((uint)ub << 16);
}

// ---------------------------------------------------------------------------
// Kernel 1: projections q_t = norm(h_t @ Wq[t]^T), k_e = norm(h_pred @ Wk[e]^T)
// (bf16 out), plus vT[p][b][h][n] = bf16 transpose of h_p.
// grid = 128 rowtiles x 3 slices.
// ---------------------------------------------------------------------------
__global__ __launch_bounds__(256) void prep_kernel(
    const float* __restrict__ h0, const float* __restrict__ h1, const float* __restrict__ h2,
    const float* __restrict__ Wq, const float* __restrict__ Wk,
    bf16* __restrict__ qn, bf16* __restrict__ kn, bf16* __restrict__ vT)
{
    __shared__ __align__(16) unsigned short tlds[4][16][72];
    const int tid = threadIdx.x, wid = tid >> 6, lane = tid & 63;
    const int l15 = lane & 15, quad = lane >> 4;
    const int bx = blockIdx.x;
    const int rt = bx & 127, sl = bx >> 7;       // slice 0..2
    const int g0 = rt * 64;
    const int grow = g0 + wid * 16 + l15;        // A-frag row (global b*N+n)
    const float* hs[3] = {h0, h1, h2};

    bf16x8 af[3][2];
#pragma unroll
    for (int p = 0; p < 3; p++)
#pragma unroll
        for (int hc = 0; hc < 2; hc++)
            af[p][hc] = ld8f(hs[p] + (size_t)grow * 64 + hc * 32 + quad * 8);

    if (sl == 0) {
        const int gr0 = g0 + wid * 16;
        const int bb = gr0 >> 12, n0 = gr0 & 4095;
#pragma unroll
        for (int p = 0; p < 3; p++) {
#pragma unroll
            for (int hc = 0; hc < 2; hc++)
                *(u16x8*)(&tlds[wid][l15][hc * 32 + quad * 8]) = __builtin_bit_cast(u16x8, af[p][hc]);
            unsigned short vals[16];
#pragma unroll
            for (int r = 0; r < 16; r++) vals[r] = tlds[wid][r][lane];
            uint us[8];
#pragma unroll
            for (int k = 0; k < 8; k++) us[k] = (uint)vals[2 * k] | ((uint)vals[2 * k + 1] << 16);
            uint* dst = (uint*)(vT + ((size_t)(p * 2 + bb) * 64 + lane) * NT + n0);
            u32x4 w0 = {us[0], us[1], us[2], us[3]};
            u32x4 w1 = {us[4], us[5], us[6], us[7]};
            *(u32x4*)dst = w0;
            *(u32x4*)(dst + 4) = w1;
        }
    }

    const int predmap[6] = {0, 2, 0, 1, 1, 2};
    const int pj0 = sl * 3;
#pragma unroll
    for (int pi = 0; pi < 3; pi++) {
        const int pj = pj0 + pi;
        const float* W = (pj < 3) ? (Wq + pj * 4096) : (Wk + (pj - 3) * 4096);
        const int src = (pj < 3) ? pj : predmap[pj - 3];
        bf16* outp = (pj < 3) ? (qn + (size_t)pj * 2 * NT * 64)
                              : (kn + (size_t)(pj - 3) * 2 * NT * 64);
        f32x4 s[4];
#pragma unroll
        for (int it = 0; it < 4; it++) {
            f32x4 acc = {0.f, 0.f, 0.f, 0.f};
#pragma unroll
            for (int hc = 0; hc < 2; hc++) {
                bf16x8 wb = ld8f(W + (size_t)(it * 16 + l15) * 64 + hc * 32 + quad * 8);
                acc = __builtin_amdgcn_mfma_f32_16x16x32_bf16(af[src][hc], wb, acc, 0, 0, 0);
            }
            s[it] = acc;
        }
#pragma unroll
        for (int r = 0; r < 4; r++) {
            float ss = s[0][r] * s[0][r] + s[1][r] * s[1][r] + s[2][r] * s[2][r] + s[3][r] * s[3][r];
            ss += __shfl_xor(ss, 1); ss += __shfl_xor(ss, 2);
            ss += __shfl_xor(ss, 4); ss += __shfl_xor(ss, 8);
            float rn = rsqrtf(ss);
            s[0][r] *= rn; s[1][r] *= rn; s[2][r] *= rn; s[3][r] *= rn;
        }
        const int rowbase = g0 + wid * 16 + quad * 4;
#pragma unroll
        for (int it = 0; it < 4; it++)
#pragma unroll
            for (int r = 0; r < 4; r++)
                outp[(size_t)(rowbase + r) * 64 + it * 16 + l15] = (bf16)s[it][r];
    }
}

// ---------------------------------------------------------------------------
// Kernel 2: masked cosine attention (round-2 LDS-staged structure) with a
// register-prefetch software pipeline:
//   - K/V staging lines for iter i+1 are loaded into VGPRs right after the
//     post-write barrier of iter i (in flight during the whole compute phase)
//   - mask fragments for iter i+1 load right after stage-1's last use
// Unscaled fp32 partials stored coalesced in [chunk][e][b][h][n] layout.
// grid = 6 edges * 32 q-tiles(128 rows) * JC.  3 blocks/CU.
// ---------------------------------------------------------------------------
template<int JC>
__global__ __launch_bounds__(256, 3) void attn_kernel(
    const bf16* __restrict__ qn, const bf16* __restrict__ kn, const bf16* __restrict__ vT,
    const float* __restrict__ m00, const float* __restrict__ m20, const float* __restrict__ m01,
    const float* __restrict__ m11, const float* __restrict__ m12, const float* __restrict__ m22,
    float* __restrict__ Pacc, float* __restrict__ rsO)
{
    __shared__ __align__(16) bf16 Klds[2][64][72];
    __shared__ __align__(16) bf16 Vlds[2][64][72];
    const int tid = threadIdx.x, wid = tid >> 6, lane = tid & 63;
    const int l15 = lane & 15, quad = lane >> 4;
    const int bx = blockIdx.x;
    const int e = bx / (32 * JC);
    const int rem = bx % (32 * JC);
    const int qt = rem / JC, jcv = rem % JC;
    const int qrow0 = qt * 128, wstrip = wid * 32;
    const int qtypemap[6] = {0, 0, 1, 1, 2, 2};
    const int predmap[6]  = {0, 2, 0, 1, 1, 2};
    const float* masks[6] = {m00, m20, m01, m11, m12, m22};
    const float* __restrict__ mask = masks[e];
    const int qtv = qtypemap[e], pv = predmap[e];
    constexpr int JSPAN = NT / JC;
    constexpr int NI = JSPAN / 64;
    const int jbeg = jcv * JSPAN;

    // per-thread staging line mapping (4 K lines + 4 V lines per thread)
    int s_b[4], s_jl[4], s_ch[4];
#pragma unroll
    for (int i = 0; i < 4; i++) {
        int u = tid + 256 * i;
        s_b[i] = u >> 9; s_jl[i] = (u >> 3) & 63; s_ch[i] = u & 7;
    }

    // Q fragments (stage-1 B-operand), register resident
    bf16x8 Qf[2][2][2];
#pragma unroll
    for (int b = 0; b < 2; b++)
#pragma unroll
        for (int mt = 0; mt < 2; mt++)
#pragma unroll
            for (int hc = 0; hc < 2; hc++)
                Qf[b][mt][hc] = *(const bf16x8*)(qn +
                    ((size_t)(qtv * 2 + b) * NT + qrow0 + wstrip + mt * 16 + l15) * 64 +
                    hc * 32 + quad * 8);

    f32x4 acc2[2][4][2];   // [b][ht][mt]  (acc^T: row=h, col=query)
#pragma unroll
    for (int b = 0; b < 2; b++)
#pragma unroll
        for (int ht = 0; ht < 4; ht++)
#pragma unroll
            for (int mt = 0; mt < 2; mt++) {
                f32x4 z = {0.f, 0.f, 0.f, 0.f};
                acc2[b][ht][mt] = z;
            }
    float rsl[2] = {0.f, 0.f};

    // ---- preload staging + mask regs for first iteration ----
    u32x4 kreg[4], vreg[4];
#pragma unroll
    for (int i = 0; i < 4; i++) {
        kreg[i] = *(const u32x4*)(kn + ((size_t)(e * 2 + s_b[i]) * NT + jbeg + s_jl[i]) * 64 + s_ch[i] * 8);
        vreg[i] = *(const u32x4*)(vT + ((size_t)(pv * 2 + s_b[i]) * 64 + s_jl[i]) * NT + jbeg + s_ch[i] * 8);
    }
    f32x4 mv[2][4];
#pragma unroll
    for (int mt = 0; mt < 2; mt++)
#pragma unroll
        for (int jt = 0; jt < 4; jt++)
            mv[mt][jt] = *(const f32x4*)(mask +
                (size_t)(qrow0 + wstrip + mt * 16 + l15) * NT + jbeg + jt * 16 + quad * 4);

#pragma unroll 1
    for (int ji = 0; ji < NI; ji++) {
        const int jn = (ji + 1 < NI) ? (jbeg + (ji + 1) * 64) : jbeg;   // next (clamped)

        __syncthreads();                           // prior compute done reading LDS
#pragma unroll
        for (int i = 0; i < 4; i++) {
            *(u32x4*)(&Klds[s_b[i]][s_jl[i]][s_ch[i] * 8]) = kreg[i];
            *(u32x4*)(&Vlds[s_b[i]][s_jl[i]][s_ch[i] * 8]) = vreg[i];
        }
        __syncthreads();                           // staged tile visible

        // issue next iteration's staging loads — in flight during compute
#pragma unroll
        for (int i = 0; i < 4; i++) {
            kreg[i] = *(const u32x4*)(kn + ((size_t)(e * 2 + s_b[i]) * NT + jn + s_jl[i]) * 64 + s_ch[i] * 8);
            vreg[i] = *(const u32x4*)(vT + ((size_t)(pv * 2 + s_b[i]) * 64 + s_jl[i]) * NT + jn + s_ch[i] * 8);
        }

        // mask rowsums (current mv)
#pragma unroll
        for (int mt = 0; mt < 2; mt++)
#pragma unroll
            for (int jt = 0; jt < 4; jt++)
                rsl[mt] += mv[mt][jt][0] + mv[mt][jt][1] + mv[mt][jt][2] + mv[mt][jt][3];

        // stage 1 for BOTH batches: S^T tiles, mask, pack bf16 pairs
        uint Pd[2][4][2][2];    // [b][jt][mt][d]
#pragma unroll
        for (int jt = 0; jt < 4; jt++)
#pragma unroll
            for (int b = 0; b < 2; b++)
#pragma unroll
                for (int mt = 0; mt < 2; mt++) {
                    f32x4 sc = {0.f, 0.f, 0.f, 0.f};
#pragma unroll
                    for (int hc = 0; hc < 2; hc++) {
                        bf16x8 a = *(const bf16x8*)(&Klds[b][jt * 16 + l15][hc * 32 + quad * 8]);
                        sc = __builtin_amdgcn_mfma_f32_16x16x32_bf16(a, Qf[b][mt][hc], sc, 0, 0, 0);
                    }
                    sc[0] *= mv[mt][jt][0]; sc[1] *= mv[mt][jt][1];
                    sc[2] *= mv[mt][jt][2]; sc[3] *= mv[mt][jt][3];
                    Pd[b][jt][mt][0] = pack2(sc[0], sc[1]);
                    Pd[b][jt][mt][1] = pack2(sc[2], sc[3]);
                }

        // mv's last use is above — issue next iteration's mask loads now
#pragma unroll
        for (int mt = 0; mt < 2; mt++)
#pragma unroll
            for (int jt = 0; jt < 4; jt++)
                mv[mt][jt] = *(const f32x4*)(mask +
                    (size_t)(qrow0 + wstrip + mt * 16 + l15) * NT + jn + jt * 16 + quad * 4);

        // stage 2 per batch: B-frags via ds_bpermute, then acc^T += VT·P^T
#pragma unroll
        for (int b = 0; b < 2; b++) {
            uint Bf[2][2][4];    // [mt][c][v]
#pragma unroll
            for (int mt = 0; mt < 2; mt++)
#pragma unroll
                for (int c = 0; c < 2; c++)
#pragma unroll
                    for (int v = 0; v < 4; v++) {
                        int srclane = ((((quad & 1) * 2 + (v >> 1)) * 16 + l15) << 2);
                        int lo = __builtin_amdgcn_ds_bpermute(srclane, (int)Pd[b][2 * c][mt][v & 1]);
                        int hi = __builtin_amdgcn_ds_bpermute(srclane, (int)Pd[b][2 * c + 1][mt][v & 1]);
                        Bf[mt][c][v] = (quad & 2) ? (uint)hi : (uint)lo;
                    }
#pragma unroll
            for (int ht = 0; ht < 4; ht++)
#pragma unroll
                for (int c = 0; c < 2; c++) {
                    bf16x8 a = *(const bf16x8*)(&Vlds[b][ht * 16 + l15][c * 32 + quad * 8]);
#pragma unroll
                    for (int mt = 0; mt < 2; mt++) {
                        u32x4 t = {Bf[mt][c][0], Bf[mt][c][1], Bf[mt][c][2], Bf[mt][c][3]};
                        bf16x8 bbv = __builtin_bit_cast(bf16x8, t);
                        acc2[b][ht][mt] =
                            __builtin_amdgcn_mfma_f32_16x16x32_bf16(a, bbv, acc2[b][ht][mt], 0, 0, 0);
                    }
                }
        }
    }

    // coalesced fp32 partial store: Pacc[chunk][e][b][h][n]
    // lane (quad,r) -> h = ht*16+quad*4+r ; lanes l15 -> 16 consecutive n (64B)
#pragma unroll
    for (int b = 0; b < 2; b++)
#pragma unroll
        for (int ht = 0; ht < 4; ht++)
#pragma unroll
            for (int mt = 0; mt < 2; mt++) {
                const int n = qrow0 + wstrip + mt * 16 + l15;
#pragma unroll
                for (int r = 0; r < 4; r++) {
                    const int h = ht * 16 + quad * 4 + r;
                    Pacc[(((size_t)(jcv * 6 + e) * 2 + b) * 64 + h) * NT + n] = acc2[b][ht][mt][r];
                }
            }
    // mask rowsums: quads hold disjoint j segments
#pragma unroll
    for (int mt = 0; mt < 2; mt++) {
        float v = rsl[mt];
        v += __shfl_xor(v, 16);
        v += __shfl_xor(v, 32);
        if (quad == 0)
            rsO[(size_t)(jcv * 6 + e) * NT + qrow0 + wstrip + mt * 16 + l15] = v;
    }
}

// ---------------------------------------------------------------------------
// Kernel 3: combine fp32 partials over JC chunks (acc_t = ΣP/Σrs per edge),
// dt_t = 2*sigmoid(h_t Wdt_t^T + b) - 1, h_tn = h_t + step*dt*u_t, outputs.
// Pacc layout [chunk][e][b][h][n]: reads are lane-coalesced over n.
// grid = 128 rowtiles x 3 types.
// ---------------------------------------------------------------------------
template<int JC>
__global__ __launch_bounds__(256) void update_kernel(
    const float* __restrict__ x0, const float* __restrict__ h0,
    const float* __restrict__ h1, const float* __restrict__ h2,
    const float* __restrict__ Wsu0, const float* __restrict__ Wsu12,
    const float* __restrict__ Wdt, const float* __restrict__ bdt,
    const float* __restrict__ stepp, const float* __restrict__ oscp,
    const float* __restrict__ Pacc, const float* __restrict__ rs,
    float* __restrict__ dout)
{
    const int tid = threadIdx.x, wid = tid >> 6, lane = tid & 63;
    const int l15 = lane & 15, quad = lane >> 4;
    const int bx = blockIdx.x;
    const int rt = bx & 127, t = bx >> 7;
    const int g0 = rt * 64;
    const int grow = g0 + wid * 16 + l15;
    const int n = grow & 4095, bb = grow >> 12;
    const float step = *stepp, osc = *oscp;
    const float* hs[3] = {h0, h1, h2};
    const float* __restrict__ ht_base = hs[t];

    bf16x8 afh[2], afacc[2], afx;
#pragma unroll
    for (int hc = 0; hc < 2; hc++)
        afh[hc] = ld8f(ht_base + (size_t)grow * 64 + hc * 32 + quad * 8);
    if (t == 0) afx = ld8f(x0 + (size_t)grow * 32 + quad * 8);

    float s0 = 0.f, s1 = 0.f;
#pragma unroll
    for (int jc = 0; jc < JC; jc++) {
        s0 += rs[(size_t)(jc * 6 + 2 * t) * NT + n];
        s1 += rs[(size_t)(jc * 6 + 2 * t + 1) * NT + n];
    }
    const float i0 = 1.f / s0, i1 = 1.f / s1;
#pragma unroll
    for (int hc = 0; hc < 2; hc++) {
        float S0[8] = {0,0,0,0,0,0,0,0}, S1[8] = {0,0,0,0,0,0,0,0};
#pragma unroll
        for (int jc = 0; jc < JC; jc++) {
            const float* b0 = Pacc + (((size_t)(jc * 6 + 2 * t) * 2 + bb) * 64) * NT + n;
            const float* b1 = Pacc + (((size_t)(jc * 6 + 2 * t + 1) * 2 + bb) * 64) * NT + n;
#pragma unroll
            for (int j = 0; j < 8; j++) {
                const int h = hc * 32 + quad * 8 + j;
                S0[j] += b0[(size_t)h * NT];
                S1[j] += b1[(size_t)h * NT];
            }
        }
        bf16x8 v;
#pragma unroll
        for (int j = 0; j < 8; j++) v[j] = (bf16)(S0[j] * i0 + S1[j] * i1);
        afacc[hc] = v;
    }

    float bdtv[4];
#pragma unroll
    for (int it = 0; it < 4; it++)
        bdtv[it] = bdt[t * 64 + it * 16 + l15];

#pragma unroll
    for (int it = 0; it < 4; it++) {
        f32x4 z = {0.f, 0.f, 0.f, 0.f};
        f32x4 u = {0.f, 0.f, 0.f, 0.f};
#pragma unroll
        for (int hc = 0; hc < 2; hc++) {
            bf16x8 wb = ld8f(Wdt + (size_t)t * 4096 + (size_t)(it * 16 + l15) * 64 + hc * 32 + quad * 8);
            z = __builtin_amdgcn_mfma_f32_16x16x32_bf16(afh[hc], wb, z, 0, 0, 0);
        }
        if (t == 0) {
            bf16x8 w0 = ld8f(Wsu0 + (size_t)(it * 16 + l15) * 96 + quad * 8);
            u = __builtin_amdgcn_mfma_f32_16x16x32_bf16(afx, w0, u, 0, 0, 0);
#pragma unroll
            for (int kc = 0; kc < 2; kc++) {
                bf16x8 wk = ld8f(Wsu0 + (size_t)(it * 16 + l15) * 96 + 32 + kc * 32 + quad * 8);
                u = __builtin_amdgcn_mfma_f32_16x16x32_bf16(afacc[kc], wk, u, 0, 0, 0);
            }
        } else {
#pragma unroll
            for (int kc = 0; kc < 2; kc++) {
                bf16x8 wk = ld8f(Wsu12 + (size_t)(t - 1) * 4096 + (size_t)(it * 16 + l15) * 64 + kc * 32 + quad * 8);
                u = __builtin_amdgcn_mfma_f32_16x16x32_bf16(afacc[kc], wk, u, 0, 0, 0);
            }
        }
        const int colg = it * 16 + l15;
#pragma unroll
        for (int r = 0; r < 4; r++) {
            int row = g0 + wid * 16 + quad * 4 + r;
            float zz = z[r] + bdtv[it];
            float dtv = 2.f / (1.f + __expf(-zz)) - 1.f;
            float hval = ht_base[(size_t)row * 64 + colg];
            float hn = hval + step * dtv * u[r];
            dout[65536 + (size_t)t * 524288 + (size_t)row * 64 + colg] = hn;
            if (t == 2 && colg < 8)
                dout[(size_t)row * 8 + colg] = osc * hn;
        }
    }
}

extern "C" void kernel_launch(void* const* d_in, const int* in_sizes, int n_in,
                              void* d_out, int out_size, void* d_ws, size_t ws_size,
                              hipStream_t stream) {
    const float* x0   = (const float*)d_in[0];
    const float* h0   = (const float*)d_in[1];
    const float* h1   = (const float*)d_in[2];
    const float* h2   = (const float*)d_in[3];
    const float* m00  = (const float*)d_in[4];
    const float* m20  = (const float*)d_in[5];
    const float* m01  = (const float*)d_in[6];
    const float* m11  = (const float*)d_in[7];
    const float* m12  = (const float*)d_in[8];
    const float* m22  = (const float*)d_in[9];
    const float* Wq   = (const float*)d_in[10];
    const float* Wk   = (const float*)d_in[11];
    const float* Wsu0 = (const float*)d_in[12];
    const float* Wsu12= (const float*)d_in[13];
    const float* Wdt  = (const float*)d_in[14];
    const float* bdt  = (const float*)d_in[15];
    const float* step = (const float*)d_in[16];
    const float* oscl = (const float*)d_in[17];

    // workspace layout (element counts)
    bf16* qn  = (bf16*)d_ws;                    // 3*2*4096*64 = 1,572,864
    bf16* kn  = qn + 1572864;                   // 6*2*4096*64 = 3,145,728
    bf16* vT  = kn + 3145728;                   // 3*2*64*4096 = 1,572,864
    float* Pacc = (float*)(vT + 1572864);       // JC*6*2*64*4096 floats
    // rs follows: JC*6*4096 floats

    // bytes: 12,582,912 + JC*12,582,912 (Pacc) + JC*98,304 (rs)
    auto need = [](size_t jc) { return 12582912 + jc * 12582912 + jc * 98304; };
    const int JC = (ws_size >= need(4)) ? 4 : ((ws_size >= need(2)) ? 2 : 1);

    prep_kernel<<<384, 256, 0, stream>>>(h0, h1, h2, Wq, Wk, qn, kn, vT);

    if (JC == 4) {
        float* rs = Pacc + (size_t)4 * 3145728;
        attn_kernel<4><<<6 * 32 * 4, 256, 0, stream>>>(qn, kn, vT, m00, m20, m01, m11, m12, m22, Pacc, rs);
        update_kernel<4><<<384, 256, 0, stream>>>(x0, h0, h1, h2, Wsu0, Wsu12, Wdt, bdt,
                                                  step, oscl, Pacc, rs, (float*)d_out);
    } else if (JC == 2) {
        float* rs = Pacc + (size_t)2 * 3145728;
        attn_kernel<2><<<6 * 32 * 2, 256, 0, stream>>>(qn, kn, vT, m00, m20, m01, m11, m12, m22, Pacc, rs);
        update_kernel<2><<<384, 256, 0, stream>>>(x0, h0, h1, h2, Wsu0, Wsu12, Wdt, bdt,
                                                  step, oscl, Pacc, rs, (float*)d_out);
    } else {
        float* rs = Pacc + (size_t)1 * 3145728;
        attn_kernel<1><<<6 * 32 * 1, 256, 0, stream>>>(qn, kn, vT, m00, m20, m01, m11, m12, m22, Pacc, rs);
        update_kernel<1><<<384, 256, 0, stream>>>(x0, h0, h1, h2, Wsu0, Wsu12, Wdt, bdt,
                                                  step, oscl, Pacc, rs, (float*)d_out);
    }
}